// Round 1
// baseline (263.221 us; speedup 1.0000x reference)
//
#include <hip/hip_runtime.h>
#include <math.h>

#define EPSF 1e-7f

__device__ __forceinline__ float wave_reduce_sum(float v) {
    #pragma unroll
    for (int o = 32; o > 0; o >>= 1) v += __shfl_xor(v, o, 64);
    return v;
}

// K1: x_tan = logmap0(x_hyp, c_sphere). One block per row.
__global__ void k_logmap(const float* __restrict__ x, const float* __restrict__ c_sphere,
                         float* __restrict__ x_tan, int N, int D) {
    int row = blockIdx.x;
    const float* xr = x + (size_t)row * D;
    float* outr = x_tan + (size_t)row * D;
    float c = c_sphere[0];
    float sqc = fmaxf(sqrtf(c), EPSF);
    float ss = 0.f;
    for (int i = threadIdx.x; i < D; i += blockDim.x) { float v = xr[i]; ss += v * v; }
    __shared__ float red[4];
    ss = wave_reduce_sum(ss);
    int lane = threadIdx.x & 63, wave = threadIdx.x >> 6;
    if (lane == 0) red[wave] = ss;
    __syncthreads();
    ss = red[0] + red[1] + red[2] + red[3];
    float yn = sqrtf(ss);
    float scale;
    if (yn < EPSF) scale = 0.f;
    else scale = atanhf(fminf(yn, 1.f - EPSF)) / sqc / fmaxf(yn, EPSF);
    for (int i = threadIdx.x; i < D; i += blockDim.x) outr[i] = xr[i] * scale;
}

// Generic fp32 tiled GEMM: C[M,N] = A[M,K] @ B[K,N] + bias[N]
// 64x64 tile, BK=16, 256 threads, 4x4 micro-tile per thread.
__global__ void k_gemm_bias(const float* __restrict__ A, const float* __restrict__ B,
                            const float* __restrict__ bias, float* __restrict__ C,
                            int M, int N, int K) {
    __shared__ float As[16][65];
    __shared__ float Bs[16][65];
    int tid = threadIdx.x;
    int tx = tid & 15, ty = tid >> 4;
    int row0 = blockIdx.y * 64, col0 = blockIdx.x * 64;
    float acc[4][4] = {};
    for (int k0 = 0; k0 < K; k0 += 16) {
        #pragma unroll
        for (int r = 0; r < 4; ++r) {
            int e = tid + r * 256;
            int m = e >> 4, kk = e & 15;
            As[kk][m] = A[(size_t)(row0 + m) * K + k0 + kk];
        }
        #pragma unroll
        for (int r = 0; r < 4; ++r) {
            int e = tid + r * 256;
            int kk = e >> 6, n = e & 63;
            Bs[kk][n] = B[(size_t)(k0 + kk) * N + col0 + n];
        }
        __syncthreads();
        #pragma unroll
        for (int kk = 0; kk < 16; ++kk) {
            float a[4], b[4];
            #pragma unroll
            for (int i = 0; i < 4; ++i) a[i] = As[kk][ty * 4 + i];
            #pragma unroll
            for (int j = 0; j < 4; ++j) b[j] = Bs[kk][tx * 4 + j];
            #pragma unroll
            for (int i = 0; i < 4; ++i)
                #pragma unroll
                for (int j = 0; j < 4; ++j)
                    acc[i][j] += a[i] * b[j];
        }
        __syncthreads();
    }
    #pragma unroll
    for (int i = 0; i < 4; ++i) {
        int r = row0 + ty * 4 + i;
        #pragma unroll
        for (int j = 0; j < 4; ++j) {
            int cidx = col0 + tx * 4 + j;
            C[(size_t)r * N + cidx] = acc[i][j] + bias[cidx];
        }
    }
}

// K3: RoPE on q,k; expmap0(q_rot), expmap0(k_rot); relayout v.
// One wave (64 lanes) per (h,n) vector. 4 waves/block.
// Outputs: qh/kh/v in [H][N][64] layout, squared norms x2q/y2k in [H][N].
__global__ void k_rope_expmap(const float* __restrict__ qkv, const float* __restrict__ freqs,
                              const float* __restrict__ c_logits,
                              float* __restrict__ qh, float* __restrict__ kh,
                              float* __restrict__ vout,
                              float* __restrict__ x2q, float* __restrict__ y2k) {
    const int N = 512;
    int wave = threadIdx.x >> 6, lane = threadIdx.x & 63;
    int vec = blockIdx.x * 4 + wave;     // vec = h*N + n
    int h = vec >> 9;
    int n = vec & 511;
    float c = log1pf(expf(c_logits[h]));
    float sqc = fmaxf(sqrtf(c), EPSF);
    int j = lane & 31;
    float f = freqs[n * 32 + j];
    float cs = cosf(f), sn = sinf(f);
    const float* base = qkv + (size_t)n * 1536;
    size_t oidx = ((size_t)h * N + n) * 64 + lane;

    // ---- q ----
    {
        float qa = base[h * 64 + lane];
        float qb = base[h * 64 + (lane ^ 32)];
        float qr = (lane < 32) ? (qa * cs - qb * sn) : (qa * cs + qb * sn);
        float vn2 = wave_reduce_sum(qr * qr);
        float vn = sqrtf(vn2);
        float scale, fn;
        if (vn < EPSF) { scale = 0.f; fn = 0.f; }
        else {
            float mag = tanhf(sqc * vn) / sqc;
            scale = mag / fmaxf(vn, EPSF);
            fn = mag;
            if (fn >= 1.f) { scale *= (1.f - EPSF) / fn; fn = 1.f - EPSF; }
        }
        qh[oidx] = qr * scale;
        if (lane == 0) x2q[h * N + n] = fn * fn;
    }
    // ---- k ----
    {
        float ka = base[512 + h * 64 + lane];
        float kb = base[512 + h * 64 + (lane ^ 32)];
        float kr = (lane < 32) ? (ka * cs - kb * sn) : (ka * cs + kb * sn);
        float vn2 = wave_reduce_sum(kr * kr);
        float vn = sqrtf(vn2);
        float scale, fn;
        if (vn < EPSF) { scale = 0.f; fn = 0.f; }
        else {
            float mag = tanhf(sqc * vn) / sqc;
            scale = mag / fmaxf(vn, EPSF);
            fn = mag;
            if (fn >= 1.f) { scale *= (1.f - EPSF) / fn; fn = 1.f - EPSF; }
        }
        kh[oidx] = kr * scale;
        if (lane == 0) y2k[h * N + n] = fn * fn;
    }
    // ---- v relayout ----
    vout[oidx] = base[1024 + h * 64 + lane];
}

// K4: attention. One block (256 threads) per (qi, h).
// Hyperbolic distance from (dot, x2, y2) only:
//   a = 1 - 2c*dot + c*y2; b = 1 - c*x2
//   |num|^2 = a^2*x2 + b^2*y2 - 2ab*dot;  den = 1 - 2c*dot + c^2*x2*y2
__global__ void k_attn(const float* __restrict__ qh, const float* __restrict__ kh,
                       const float* __restrict__ v,
                       const float* __restrict__ x2q, const float* __restrict__ y2k,
                       const float* __restrict__ c_logits, const float* __restrict__ geo_scale,
                       float* __restrict__ aout) {
    const int N = 512;
    int qi = blockIdx.x;
    int h = blockIdx.y;
    int tid = threadIdx.x;
    __shared__ float qrow[64];
    __shared__ float sc[512];
    __shared__ float red4[4];
    __shared__ float pv[4][64];
    float c = log1pf(expf(c_logits[h]));
    float sqc = fmaxf(sqrtf(c), EPSF);
    float gs = geo_scale[h];
    const float* khb = kh + (size_t)h * N * 64;
    if (tid < 64) qrow[tid] = qh[((size_t)h * N + qi) * 64 + tid];
    __syncthreads();
    float x2 = x2q[h * N + qi];
    float b = 1.f - c * x2;

    float lmax = -INFINITY;
    for (int ki = tid; ki < N; ki += 256) {
        float s;
        if (ki <= qi) {
            const float* kr = khb + (size_t)ki * 64;
            float dot = 0.f;
            #pragma unroll
            for (int d = 0; d < 64; ++d) dot += qrow[d] * kr[d];
            float y2 = y2k[h * N + ki];
            float a = 1.f + c * (y2 - 2.f * dot);
            float num2 = a * a * x2 + b * b * y2 - 2.f * a * b * dot;
            float den = fmaxf(1.f - 2.f * c * dot + c * c * x2 * y2, EPSF);
            float nrm = sqrtf(fmaxf(num2, 0.f)) / den;
            if (nrm >= 1.f) nrm = 1.f - EPSF;
            float arg = fminf(sqc * nrm, 1.f - EPSF);
            s = -gs * (2.f * atanhf(arg) / sqc);
        } else {
            s = -INFINITY;
        }
        sc[ki] = s;
        lmax = fmaxf(lmax, s);
    }
    // block max
    #pragma unroll
    for (int o = 32; o > 0; o >>= 1) lmax = fmaxf(lmax, __shfl_xor(lmax, o, 64));
    int lane = tid & 63, wave = tid >> 6;
    if (lane == 0) red4[wave] = lmax;
    __syncthreads();
    float m = fmaxf(fmaxf(red4[0], red4[1]), fmaxf(red4[2], red4[3]));
    __syncthreads();
    // exp + sum (unnormalized weights stored back into sc)
    float lsum = 0.f;
    for (int ki = tid; ki < N; ki += 256) {
        float p = expf(sc[ki] - m);
        sc[ki] = p;
        lsum += p;
    }
    lsum = wave_reduce_sum(lsum);
    if (lane == 0) red4[wave] = lsum;
    __syncthreads();
    float ssum = red4[0] + red4[1] + red4[2] + red4[3];
    // PV: thread (d, chunk) layout
    int d = tid & 63, c4 = tid >> 6;
    const float* vb = v + (size_t)h * N * 64;
    float acc = 0.f;
    int k0 = c4 * 128;
    int kend = min(k0 + 128, qi + 1);
    for (int ki = k0; ki < kend; ++ki) acc += sc[ki] * vb[(size_t)ki * 64 + d];
    pv[c4][d] = acc;
    __syncthreads();
    if (tid < 64) {
        float o = (pv[0][tid] + pv[1][tid] + pv[2][tid] + pv[3][tid]) / ssum;
        aout[(size_t)qi * 512 + h * 64 + tid] = o;   // [n][h*64+d] layout for final GEMM
    }
}

extern "C" void kernel_launch(void* const* d_in, const int* in_sizes, int n_in,
                              void* d_out, int out_size, void* d_ws, size_t ws_size,
                              hipStream_t stream) {
    const float* x_hyp     = (const float*)d_in[0];
    const float* freqs     = (const float*)d_in[1];
    const float* c_sphere  = (const float*)d_in[2];
    const float* w_qkv     = (const float*)d_in[3];
    const float* b_qkv     = (const float*)d_in[4];
    const float* w_out     = (const float*)d_in[5];
    const float* b_out     = (const float*)d_in[6];
    const float* c_logits  = (const float*)d_in[7];
    const float* geo_scale = (const float*)d_in[8];
    float* out = (float*)d_out;
    float* ws  = (float*)d_ws;

    const int N = 512, D = 512, H = 8;
    float* x_tan = ws;                       // 512*512
    float* qkv   = x_tan + N * D;            // 512*1536
    float* qh    = qkv + N * 1536;           // 8*512*64
    float* kh2   = qh + H * N * 64;          // 8*512*64
    float* vv    = kh2 + H * N * 64;         // 8*512*64
    float* x2q   = vv + H * N * 64;          // 8*512
    float* y2k   = x2q + H * N;              // 8*512
    float* aout  = y2k + H * N;              // 512*512

    k_logmap<<<N, 256, 0, stream>>>(x_hyp, c_sphere, x_tan, N, D);
    k_gemm_bias<<<dim3(1536 / 64, N / 64), 256, 0, stream>>>(x_tan, w_qkv, b_qkv, qkv, N, 1536, D);
    k_rope_expmap<<<(H * N) / 4, 256, 0, stream>>>(qkv, freqs, c_logits, qh, kh2, vv, x2q, y2k);
    k_attn<<<dim3(N, H), 256, 0, stream>>>(qh, kh2, vv, x2q, y2k, c_logits, geo_scale, aout);
    k_gemm_bias<<<dim3(D / 64, N / 64), 256, 0, stream>>>(aout, w_out, b_out, out, N, D, D);
}